// Round 4
// baseline (1386.227 us; speedup 1.0000x reference)
//
#include <hip/hip_runtime.h>
#include <stdint.h>
#include <stddef.h>

#define NB 2
#define NT 4096
#define NC 768
#define NH 12
#define ND 64

typedef unsigned short u16;
typedef __attribute__((ext_vector_type(4))) float f32x4;
typedef __attribute__((ext_vector_type(8))) unsigned short u16x8;
typedef __attribute__((ext_vector_type(4))) unsigned short u16x4;
typedef __attribute__((ext_vector_type(8))) __bf16 bf16x8;

__device__ __forceinline__ u16 f2bf(float f) {
  uint32_t u = __builtin_bit_cast(uint32_t, f);
  u += 0x7FFFu + ((u >> 16) & 1u);   // RTNE
  return (u16)(u >> 16);
}
__device__ __forceinline__ float bf2f(u16 v) {
  return __builtin_bit_cast(float, (uint32_t)v << 16);
}
__device__ __forceinline__ bf16x8 asbf(u16x8 v) { return __builtin_bit_cast(bf16x8, v); }

// pack two f32 -> two bf16 (round-half-up) in 3 VALU ops
__device__ __forceinline__ uint32_t pkbf(float a, float b) {
  uint32_t ua = __builtin_bit_cast(uint32_t, a) + 0x8000u;
  uint32_t ub = __builtin_bit_cast(uint32_t, b) + 0x8000u;
  return __builtin_amdgcn_perm(ub, ua, 0x07060302u);
}

// ---------------- cast fp32 -> bf16 ----------------
__global__ void k_cast(const float* __restrict__ in, u16* __restrict__ out, int n4) {
  int i = blockIdx.x * blockDim.x + threadIdx.x;
  if (i < n4) {
    f32x4 v = ((const f32x4*)in)[i];
    u16x4 o;
    o[0] = f2bf(v[0]); o[1] = f2bf(v[1]); o[2] = f2bf(v[2]); o[3] = f2bf(v[3]);
    ((u16x4*)out)[i] = o;
  }
}

// -------- transpose + cast --------
__global__ void k_transpose(const float* __restrict__ in, u16* __restrict__ out,
                            int R, int Cn) {
  __shared__ float tile[32][33];
  int c0 = blockIdx.x * 32, r0 = blockIdx.y * 32;
  int tx = threadIdx.x & 31, ty = threadIdx.x >> 5;
  for (int i = ty; i < 32; i += 8)
    tile[i][tx] = in[(size_t)(r0 + i) * Cn + c0 + tx];
  __syncthreads();
  for (int i = ty; i < 32; i += 8)
    out[(size_t)(c0 + i) * R + r0 + tx] = f2bf(tile[tx][i]);
}

// -------- GEMM: C[M,N] = A[M,K] * Bt[N,K]^T --------
// EPI 1 folds kScale = log2(e)/sqrt(64) into Q on store.
template <int EPI>
__global__ __launch_bounds__(256, 2)
void k_gemm_bt(const u16* __restrict__ A, const u16* __restrict__ Bt,
               int M, int N, int K,
               u16* __restrict__ o0, u16* __restrict__ o1, u16* __restrict__ o2,
               float* __restrict__ of) {
  __shared__ u16 As[128 * 40];
  __shared__ u16 Bs[128 * 40];
  const int tid = threadIdx.x;
  const int wave = tid >> 6, lane = tid & 63, quad = lane >> 4, lc = lane & 15;
  const int wm = (wave & 1) * 64, wn = (wave >> 1) * 64;
  const int bm = blockIdx.y * 128, bn = blockIdx.x * 128;

  const int sr = tid >> 2;
  const int sc8 = (tid & 3) * 8;
  const u16* ap0 = A + (size_t)(bm + sr) * K + sc8;
  const u16* ap1 = A + (size_t)(bm + 64 + sr) * K + sc8;
  const u16* bp0 = Bt + (size_t)(bn + sr) * K + sc8;
  const u16* bp1 = Bt + (size_t)(bn + 64 + sr) * K + sc8;
  u16* asl0 = &As[sr * 40 + sc8];
  u16* asl1 = &As[(64 + sr) * 40 + sc8];
  u16* bsl0 = &Bs[sr * 40 + sc8];
  u16* bsl1 = &Bs[(64 + sr) * 40 + sc8];

  f32x4 zv = {0.f, 0.f, 0.f, 0.f};
  f32x4 acc[4][4];
#pragma unroll
  for (int i = 0; i < 4; ++i)
#pragma unroll
    for (int j = 0; j < 4; ++j) acc[i][j] = zv;

  for (int k0 = 0; k0 < K; k0 += 32) {
    u16x8 a0 = *(const u16x8*)(ap0 + k0);
    u16x8 a1 = *(const u16x8*)(ap1 + k0);
    u16x8 b0 = *(const u16x8*)(bp0 + k0);
    u16x8 b1 = *(const u16x8*)(bp1 + k0);
    __syncthreads();
    *(u16x8*)asl0 = a0;
    *(u16x8*)asl1 = a1;
    *(u16x8*)bsl0 = b0;
    *(u16x8*)bsl1 = b1;
    __syncthreads();

    bf16x8 af[4], bfv[4];
#pragma unroll
    for (int mi = 0; mi < 4; ++mi)
      af[mi] = asbf(*(const u16x8*)&As[(wm + mi * 16 + lc) * 40 + quad * 8]);
#pragma unroll
    for (int ni = 0; ni < 4; ++ni)
      bfv[ni] = asbf(*(const u16x8*)&Bs[(wn + ni * 16 + lc) * 40 + quad * 8]);
#pragma unroll
    for (int mi = 0; mi < 4; ++mi)
#pragma unroll
      for (int ni = 0; ni < 4; ++ni)
        acc[mi][ni] = __builtin_amdgcn_mfma_f32_16x16x32_bf16(af[mi], bfv[ni],
                                                              acc[mi][ni], 0, 0, 0);
  }

  const int mrow0 = bm + wm + quad * 4;
#pragma unroll
  for (int mi = 0; mi < 4; ++mi) {
    const int mbase = mrow0 + mi * 16;
#pragma unroll
    for (int ni = 0; ni < 4; ++ni) {
      const int n = bn + wn + ni * 16 + lc;
      if (EPI == 0) {
#pragma unroll
        for (int r = 0; r < 4; ++r)
          of[(size_t)(mbase + r) * N + n] = acc[mi][ni][r];
      } else {
        const int sect = n / NC;          // 0=q 1=k 2=v
        const int wn2 = n - sect * NC;
        const int h = wn2 >> 6, d = wn2 & 63;
        const int b = mbase >> 12;
        const int t = mbase & (NT - 1);
        const float sc = (sect == 0) ? 0.18033688011112042f : 1.0f;
        if (sect == 2) {
          u16x4 pk;
#pragma unroll
          for (int r = 0; r < 4; ++r) pk[r] = f2bf(acc[mi][ni][r]);
          *(u16x4*)&o2[((size_t)(b * NH + h) * ND + d) * NT + t] = pk;
        } else {
          u16* dst = (sect == 0) ? o0 : o1;
#pragma unroll
          for (int r = 0; r < 4; ++r)
            dst[((size_t)(b * NH + h) * NT + (t + r)) * ND + d] =
                f2bf(acc[mi][ni][r] * sc);
        }
      }
    }
  }
}

// -------- flash attention, causal, transposed, KV-PARITY SPLIT --------
// Block = (pair, parity). Phases qi = pair and 31-pair; within a phase the
// block processes KV tiles (32 wide) with index parity p. Additive partials
// (no max-subtraction) -> partial O^T (bf16) + partial l (fp32) to workspace.
// Grid 64 x B*H = 1536 blocks, 6 blocks/CU resident (LDS 20.8 KB, VGPR<=85).
#define LSK 72   // Ks stride (d=64 + pad 8)
#define LSV 40   // Vs/Ps stride (t=32 + pad 8)
__global__ __launch_bounds__(256, 6)
void k_attn(const u16* __restrict__ Q, const u16* __restrict__ K,
            const u16* __restrict__ Vt,
            u16* __restrict__ O0, u16* __restrict__ O1,
            float* __restrict__ Lp) {
  __shared__ u16 Ks[32 * LSK];       // [t][d]
  __shared__ u16 Vs[80 * LSV];       // [d][t]; rows 64..79 static ones/zeros
  __shared__ u16 Ps[4][32 * LSV];    // per-wave P^T as [q][t]

  const int tid = threadIdx.x;
  const int wave = tid >> 6, lane = tid & 63, quad = lane >> 4, lc = lane & 15;
  const int bh = blockIdx.y;
  const int p = blockIdx.x & 1, pair = blockIdx.x >> 1;
  const u16* Qb = Q + (size_t)bh * NT * ND;
  const u16* Kb = K + (size_t)bh * NT * ND;
  const u16* Vb = Vt + (size_t)bh * ND * NT;
  u16* Obase = (p ? O1 : O0) + (size_t)bh * NT * ND;
  float* Lbase = Lp + (size_t)p * (NB * NH * NT) + (size_t)bh * NT;

  // static Vs rows: row 64 = 1.0 (bf16), rows 65..79 = 0
  for (int idx = tid; idx < 16 * 32; idx += 256) {
    int r = idx >> 5, c = idx & 31;
    Vs[(64 + r) * LSV + c] = (r == 0) ? (u16)0x3F80 : (u16)0;
  }

  const int kr = tid >> 3, kc = (tid & 7) * 8;   // K-tile staging: 32 x 64
  const int vr = tid >> 2, vc = (tid & 3) * 8;   // V-tile staging: 64 x 32

#pragma unroll 1
  for (int ph = 0; ph < 2; ++ph) {
    const int qi = ph ? (31 - pair) : pair;
    const int q0 = qi * 128;
    const int qw = q0 + wave * 32;
    const int tend = q0 + 128;
    const int t0first = 32 * p;

    // Q as B-operand fragments (Q already scaled by log2(e)/8)
    bf16x8 bq[2][2];
#pragma unroll
    for (int nt = 0; nt < 2; ++nt)
#pragma unroll
      for (int ks = 0; ks < 2; ++ks)
        bq[nt][ks] = asbf(*(const u16x8*)(Qb + (size_t)(qw + nt * 16 + lc) * ND +
                                          ks * 32 + quad * 8));

    f32x4 zv = {0.f, 0.f, 0.f, 0.f};
    f32x4 oacc[5][2];                 // [dtile 0..3 = O^T, 4 = l row][qtile]
#pragma unroll
    for (int dt = 0; dt < 5; ++dt)
#pragma unroll
      for (int nt = 0; nt < 2; ++nt) oacc[dt][nt] = zv;

    // prefetch first K/V tile of this phase
    u16x8 kreg = *(const u16x8*)(Kb + (size_t)(t0first + kr) * ND + kc);
    u16x8 vreg = *(const u16x8*)(Vb + (size_t)vr * NT + t0first + vc);

#pragma unroll 1
    for (int t0 = t0first; t0 < tend; t0 += 64) {
      __syncthreads();
      *(u16x8*)&Ks[kr * LSK + kc] = kreg;
      *(u16x8*)&Vs[vr * LSV + vc] = vreg;
      __syncthreads();
      const int tn = t0 + 64;
      if (tn < tend) {
        kreg = *(const u16x8*)(Kb + (size_t)(tn + kr) * ND + kc);
        vreg = *(const u16x8*)(Vb + (size_t)vr * NT + tn + vc);
      }
      if (t0 > qw + 31) continue;     // fully masked for this wave

      // S^T = K Q^T  (m=t 32, n=q 32, k=d 64)
      f32x4 s[2][2];
#pragma unroll
      for (int mt = 0; mt < 2; ++mt)
#pragma unroll
        for (int nt = 0; nt < 2; ++nt) s[mt][nt] = zv;
#pragma unroll
      for (int ks = 0; ks < 2; ++ks) {
        bf16x8 ak[2];
#pragma unroll
        for (int mt = 0; mt < 2; ++mt)
          ak[mt] = asbf(*(const u16x8*)&Ks[(mt * 16 + lc) * LSK + ks * 32 + quad * 8]);
#pragma unroll
        for (int mt = 0; mt < 2; ++mt)
#pragma unroll
          for (int nt = 0; nt < 2; ++nt)
            s[mt][nt] = __builtin_amdgcn_mfma_f32_16x16x32_bf16(ak[mt], bq[nt][ks],
                                                                s[mt][nt], 0, 0, 0);
      }

      // exp2 (scale pre-folded), mask only on the diagonal tile, pack P^T
      const bool needmask = (t0 == qw);
#pragma unroll
      for (int mt = 0; mt < 2; ++mt)
#pragma unroll
        for (int nt = 0; nt < 2; ++nt) {
          float e[4];
#pragma unroll
          for (int r = 0; r < 4; ++r) {
            float v = s[mt][nt][r];
            if (needmask) {
              int tg = t0 + mt * 16 + quad * 4 + r;
              int qg = qw + nt * 16 + lc;
              v = (tg > qg) ? -1e30f : v;
            }
            e[r] = exp2f(v);
          }
          uint2 w;
          w.x = pkbf(e[0], e[1]);
          w.y = pkbf(e[2], e[3]);
          *(uint2*)&Ps[wave][(nt * 16 + lc) * LSV + mt * 16 + quad * 4] = w;
        }

      // O^T += V^T P^T  (m=d 80, n=q 32, k=t 32 -> single MFMA K-step)
      bf16x8 av[5], bp[2];
#pragma unroll
      for (int dt = 0; dt < 5; ++dt)
        av[dt] = asbf(*(const u16x8*)&Vs[(dt * 16 + lc) * LSV + quad * 8]);
#pragma unroll
      for (int nt = 0; nt < 2; ++nt)
        bp[nt] = asbf(*(const u16x8*)&Ps[wave][(nt * 16 + lc) * LSV + quad * 8]);
#pragma unroll
      for (int dt = 0; dt < 5; ++dt)
#pragma unroll
        for (int nt = 0; nt < 2; ++nt)
          oacc[dt][nt] = __builtin_amdgcn_mfma_f32_16x16x32_bf16(av[dt], bp[nt],
                                                                 oacc[dt][nt], 0, 0, 0);
    }

    // epilogue: partial O^T (bf16) + partial l (fp32)
#pragma unroll
    for (int nt = 0; nt < 2; ++nt) {
      const int qg = qw + nt * 16 + lc;
      u16* orow = Obase + (size_t)qg * ND;
#pragma unroll
      for (int dt = 0; dt < 4; ++dt) {
        uint2 w;
        w.x = pkbf(oacc[dt][nt][0], oacc[dt][nt][1]);
        w.y = pkbf(oacc[dt][nt][2], oacc[dt][nt][3]);
        *(uint2*)&orow[dt * 16 + quad * 4] = w;
      }
      if (quad == 0) Lbase[qg] = oacc[4][nt][0];
    }
  }
}

// -------- combine partials + normalize -> Y bf16 --------
__global__ void k_norm(const u16* __restrict__ O0, const u16* __restrict__ O1,
                       const float* __restrict__ Lp, u16* __restrict__ Y) {
  int idx = blockIdx.x * 256 + threadIdx.x;   // (B*H*T) rows x 16 d-groups
  int row = idx >> 4, dg = idx & 15;
  int bh = row >> 12, q = row & (NT - 1);
  int b = bh / NH, h = bh - b * NH;
  const u16x4 a0 = *(const u16x4*)(O0 + (size_t)row * ND + dg * 4);
  const u16x4 a1 = *(const u16x4*)(O1 + (size_t)row * ND + dg * 4);
  float l = Lp[row] + Lp[row + NB * NH * NT];
  float inv = 1.f / l;
  u16x4 y;
#pragma unroll
  for (int j = 0; j < 4; ++j)
    y[j] = f2bf((bf2f(a0[j]) + bf2f(a1[j])) * inv);
  *(u16x4*)&Y[((size_t)(b * NT + q)) * NC + h * 64 + dg * 4] = y;
}

extern "C" void kernel_launch(void* const* d_in, const int* in_sizes, int n_in,
                              void* d_out, int out_size, void* d_ws, size_t ws_size,
                              hipStream_t stream) {
  (void)in_sizes; (void)n_in; (void)out_size; (void)ws_size;
  const float* x = (const float*)d_in[0];
  const float* w_qkv = (const float*)d_in[1];
  const float* w_out = (const float*)d_in[2];
  float* out = (float*)d_out;

  u16* ws = (u16*)d_ws;
  const size_t XE = (size_t)NB * NT * NC;       // 6291456
  u16* xb  = ws;                                // dead after QKV -> reused as O0
  u16* wqT = xb + XE;
  u16* woT = wqT + (size_t)3 * NC * NC;
  u16* Qb  = woT + (size_t)NC * NC;
  u16* Kb  = Qb + XE;
  u16* Vtb = Kb + XE;
  u16* yb  = Vtb + XE;
  u16* O0  = xb;                                // overlay (x consumed by then)
  u16* O1  = yb + XE;
  float* Lp = (float*)(O1 + XE);                // 2 * NB*NH*NT floats

  k_cast<<<(int)(XE / 4 / 256), 256, 0, stream>>>(x, xb, (int)(XE / 4));
  k_transpose<<<dim3(3 * NC / 32, NC / 32), 256, 0, stream>>>(w_qkv, wqT, NC, 3 * NC);
  k_transpose<<<dim3(NC / 32, NC / 32), 256, 0, stream>>>(w_out, woT, NC, NC);
  k_gemm_bt<1><<<dim3(3 * NC / 128, NB * NT / 128), 256, 0, stream>>>(
      xb, wqT, NB * NT, 3 * NC, NC, Qb, Kb, Vtb, nullptr);
  k_attn<<<dim3(64, NB * NH), 256, 0, stream>>>(Qb, Kb, Vtb, O0, O1, Lp);
  k_norm<<<(NB * NH * NT * 16) / 256, 256, 0, stream>>>(O0, O1, Lp, yb);
  k_gemm_bt<0><<<dim3(NC / 128, NB * NT / 128), 256, 0, stream>>>(
      yb, woT, NB * NT, NC, NC, nullptr, nullptr, nullptr, out);
}

// Round 5
// 608.536 us; speedup vs baseline: 2.2780x; 2.2780x over previous
//
#include <hip/hip_runtime.h>
#include <stdint.h>
#include <stddef.h>

#define NB 2
#define NT 4096
#define NC 768
#define NH 12
#define ND 64

typedef unsigned short u16;
typedef __attribute__((ext_vector_type(4))) float f32x4;
typedef __attribute__((ext_vector_type(8))) unsigned short u16x8;
typedef __attribute__((ext_vector_type(4))) unsigned short u16x4;
typedef __attribute__((ext_vector_type(8))) __bf16 bf16x8;

__device__ __forceinline__ u16 f2bf(float f) {
  uint32_t u = __builtin_bit_cast(uint32_t, f);
  u += 0x7FFFu + ((u >> 16) & 1u);   // RTNE
  return (u16)(u >> 16);
}
__device__ __forceinline__ float bf2f(u16 v) {
  return __builtin_bit_cast(float, (uint32_t)v << 16);
}
__device__ __forceinline__ bf16x8 asbf(u16x8 v) { return __builtin_bit_cast(bf16x8, v); }

// pack two f32 -> two bf16, RTNE-ish (round half up): 3 VALU
__device__ __forceinline__ uint32_t pkbf(float a, float b) {
  uint32_t ua = __builtin_bit_cast(uint32_t, a) + 0x8000u;
  uint32_t ub = __builtin_bit_cast(uint32_t, b) + 0x8000u;
  return __builtin_amdgcn_perm(ub, ua, 0x07060302u);
}
// pack two f32 -> two bf16, truncating: 1 VALU (for P; num/den stay consistent)
__device__ __forceinline__ uint32_t pktr(float a, float b) {
  return __builtin_amdgcn_perm(__builtin_bit_cast(uint32_t, b),
                               __builtin_bit_cast(uint32_t, a), 0x07060302u);
}

// ---------------- cast fp32 -> bf16 ----------------
__global__ void k_cast(const float* __restrict__ in, u16* __restrict__ out, int n4) {
  int i = blockIdx.x * blockDim.x + threadIdx.x;
  if (i < n4) {
    f32x4 v = ((const f32x4*)in)[i];
    u16x4 o;
    o[0] = f2bf(v[0]); o[1] = f2bf(v[1]); o[2] = f2bf(v[2]); o[3] = f2bf(v[3]);
    ((u16x4*)out)[i] = o;
  }
}

// -------- transpose + cast --------
__global__ void k_transpose(const float* __restrict__ in, u16* __restrict__ out,
                            int R, int Cn) {
  __shared__ float tile[32][33];
  int c0 = blockIdx.x * 32, r0 = blockIdx.y * 32;
  int tx = threadIdx.x & 31, ty = threadIdx.x >> 5;
  for (int i = ty; i < 32; i += 8)
    tile[i][tx] = in[(size_t)(r0 + i) * Cn + c0 + tx];
  __syncthreads();
  for (int i = ty; i < 32; i += 8)
    out[(size_t)(c0 + i) * R + r0 + tx] = f2bf(tile[tx][i]);
}

// -------- GEMM: C[M,N] = A[M,K] * Bt[N,K]^T --------
template <int EPI>
__global__ __launch_bounds__(256, 2)
void k_gemm_bt(const u16* __restrict__ A, const u16* __restrict__ Bt,
               int M, int N, int K,
               u16* __restrict__ o0, u16* __restrict__ o1, u16* __restrict__ o2,
               float* __restrict__ of) {
  __shared__ u16 As[128 * 40];
  __shared__ u16 Bs[128 * 40];
  const int tid = threadIdx.x;
  const int wave = tid >> 6, lane = tid & 63, quad = lane >> 4, lc = lane & 15;
  const int wm = (wave & 1) * 64, wn = (wave >> 1) * 64;
  const int bm = blockIdx.y * 128, bn = blockIdx.x * 128;

  const int sr = tid >> 2;
  const int sc8 = (tid & 3) * 8;
  const u16* ap0 = A + (size_t)(bm + sr) * K + sc8;
  const u16* ap1 = A + (size_t)(bm + 64 + sr) * K + sc8;
  const u16* bp0 = Bt + (size_t)(bn + sr) * K + sc8;
  const u16* bp1 = Bt + (size_t)(bn + 64 + sr) * K + sc8;
  u16* asl0 = &As[sr * 40 + sc8];
  u16* asl1 = &As[(64 + sr) * 40 + sc8];
  u16* bsl0 = &Bs[sr * 40 + sc8];
  u16* bsl1 = &Bs[(64 + sr) * 40 + sc8];

  f32x4 zv = {0.f, 0.f, 0.f, 0.f};
  f32x4 acc[4][4];
#pragma unroll
  for (int i = 0; i < 4; ++i)
#pragma unroll
    for (int j = 0; j < 4; ++j) acc[i][j] = zv;

  for (int k0 = 0; k0 < K; k0 += 32) {
    u16x8 a0 = *(const u16x8*)(ap0 + k0);
    u16x8 a1 = *(const u16x8*)(ap1 + k0);
    u16x8 b0 = *(const u16x8*)(bp0 + k0);
    u16x8 b1 = *(const u16x8*)(bp1 + k0);
    __syncthreads();
    *(u16x8*)asl0 = a0;
    *(u16x8*)asl1 = a1;
    *(u16x8*)bsl0 = b0;
    *(u16x8*)bsl1 = b1;
    __syncthreads();

    bf16x8 af[4], bfv[4];
#pragma unroll
    for (int mi = 0; mi < 4; ++mi)
      af[mi] = asbf(*(const u16x8*)&As[(wm + mi * 16 + lc) * 40 + quad * 8]);
#pragma unroll
    for (int ni = 0; ni < 4; ++ni)
      bfv[ni] = asbf(*(const u16x8*)&Bs[(wn + ni * 16 + lc) * 40 + quad * 8]);
#pragma unroll
    for (int mi = 0; mi < 4; ++mi)
#pragma unroll
      for (int ni = 0; ni < 4; ++ni)
        acc[mi][ni] = __builtin_amdgcn_mfma_f32_16x16x32_bf16(af[mi], bfv[ni],
                                                              acc[mi][ni], 0, 0, 0);
  }

  const int mrow0 = bm + wm + quad * 4;
#pragma unroll
  for (int mi = 0; mi < 4; ++mi) {
    const int mbase = mrow0 + mi * 16;
#pragma unroll
    for (int ni = 0; ni < 4; ++ni) {
      const int n = bn + wn + ni * 16 + lc;
      if (EPI == 0) {
#pragma unroll
        for (int r = 0; r < 4; ++r)
          of[(size_t)(mbase + r) * N + n] = acc[mi][ni][r];
      } else {
        const int sect = n / NC;          // 0=q 1=k 2=v
        const int wn2 = n - sect * NC;
        const int h = wn2 >> 6, d = wn2 & 63;
        const int b = mbase >> 12;
        const int t = mbase & (NT - 1);
        const float sc = (sect == 0) ? 0.18033688011112042f : 1.0f;  // log2e/8
        if (sect == 2) {
          u16x4 pk;
#pragma unroll
          for (int r = 0; r < 4; ++r) pk[r] = f2bf(acc[mi][ni][r]);
          *(u16x4*)&o2[((size_t)(b * NH + h) * ND + d) * NT + t] = pk;
        } else {
          u16* dst = (sect == 0) ? o0 : o1;
#pragma unroll
          for (int r = 0; r < 4; ++r)
            dst[((size_t)(b * NH + h) * NT + (t + r)) * ND + d] =
                f2bf(acc[mi][ni][r] * sc);
        }
      }
    }
  }
}

// -------- flash attention, causal, transposed, 4-way CONTIGUOUS KV chunks --------
// 1536 blocks = 24 bh x 16 pairs x 4 chunks, XCD-affine (all blocks of a head on
// one XCD -> 3 MB KV per 4 MB L2). Phases qi = pair, 31-pair; chunk g covers
// KV tiles [g*(qi+1), (g+1)*(qi+1)) of width 32 -> uniform 34 tiles/block.
// Additive partials (no max-subtraction): O^T bf16 + l fp32 per chunk.
#define LSK 72   // Ks stride (d=64 + pad)
#define LSV 40   // Vs/Ps stride (t=32 + pad)
__global__ __launch_bounds__(256, 6)
void k_attn(const u16* __restrict__ Q, const u16* __restrict__ K,
            const u16* __restrict__ Vt,
            u16* __restrict__ O0, u16* __restrict__ O1,
            u16* __restrict__ O2, u16* __restrict__ O3,
            float* __restrict__ Lp) {
  __shared__ u16 Ks[32 * LSK];       // [t][d]
  __shared__ u16 Vs[80 * LSV];       // [d][t]; rows 64..79 static ones/zeros
  __shared__ u16 Ps[4][32 * LSV];    // per-wave P^T as [q][t]

  const int tid = threadIdx.x;
  const int wave = tid >> 6, lane = tid & 63, quad = lane >> 4, lc = lane & 15;
  // XCD-affine decode: dispatch round-robins linear id % 8 across XCDs
  const int bid = blockIdx.x;
  const int xcd = bid & 7, slot = bid >> 3;
  const int bh = xcd * 3 + (slot >> 6);
  const int rest = slot & 63;
  const int pair = rest >> 2, g = rest & 3;

  const int b = bh / NH, h = bh - b * NH;
  const u16* Qb = Q + (size_t)bh * NT * ND;
  const u16* Kb = K + (size_t)bh * NT * ND;
  const u16* Vb = Vt + (size_t)bh * ND * NT;
  u16* Og = (g == 0 ? O0 : g == 1 ? O1 : g == 2 ? O2 : O3) + (size_t)bh * NT * ND;
  float* Lbase = Lp + (size_t)g * (NB * NH * NT) + (size_t)bh * NT;

  // static Vs rows: row 64 = 1.0 (bf16), rows 65..79 = 0
  for (int idx = tid; idx < 16 * 32; idx += 256) {
    int r = idx >> 5, c = idx & 31;
    Vs[(64 + r) * LSV + c] = (r == 0) ? (u16)0x3F80 : (u16)0;
  }

  const int kr = tid >> 3, kc = (tid & 7) * 8;   // K staging: 32 x 64
  const int vr = tid >> 2, vc = (tid & 3) * 8;   // V staging: 64 x 32

#pragma unroll 1
  for (int ph = 0; ph < 2; ++ph) {
    const int qi = ph ? (31 - pair) : pair;
    const int q0 = qi * 128;
    const int qw = q0 + wave * 32;
    const int ts = g * (qi + 1) * 32;            // chunk start
    const int te = (g + 1) * (qi + 1) * 32;      // chunk end

    // Q as B-operand fragments (scale pre-folded into Q)
    bf16x8 bq[2][2];
#pragma unroll
    for (int nt = 0; nt < 2; ++nt)
#pragma unroll
      for (int ks = 0; ks < 2; ++ks)
        bq[nt][ks] = asbf(*(const u16x8*)(Qb + (size_t)(qw + nt * 16 + lc) * ND +
                                          ks * 32 + quad * 8));

    f32x4 zv = {0.f, 0.f, 0.f, 0.f};
    f32x4 oacc[5][2];                 // [dtile 0..3 = O^T, 4 = l row][qtile]
#pragma unroll
    for (int dt = 0; dt < 5; ++dt)
#pragma unroll
      for (int nt = 0; nt < 2; ++nt) oacc[dt][nt] = zv;

    // prefetch first K/V tile of this chunk
    u16x8 kreg = *(const u16x8*)(Kb + (size_t)(ts + kr) * ND + kc);
    u16x8 vreg = *(const u16x8*)(Vb + (size_t)vr * NT + ts + vc);

#pragma unroll 1
    for (int t0 = ts; t0 < te; t0 += 32) {
      __syncthreads();
      *(u16x8*)&Ks[kr * LSK + kc] = kreg;
      *(u16x8*)&Vs[vr * LSV + vc] = vreg;
      __syncthreads();
      const int tn = t0 + 32;
      if (tn < te) {
        kreg = *(const u16x8*)(Kb + (size_t)(tn + kr) * ND + kc);
        vreg = *(const u16x8*)(Vb + (size_t)vr * NT + tn + vc);
      }
      if (t0 > qw + 31) continue;     // fully masked for this wave

      // S^T = K Q^T  (m=t 32, n=q 32, k=d 64)
      f32x4 s[2][2];
#pragma unroll
      for (int mt = 0; mt < 2; ++mt)
#pragma unroll
        for (int nt = 0; nt < 2; ++nt) s[mt][nt] = zv;
#pragma unroll
      for (int ks = 0; ks < 2; ++ks) {
        bf16x8 ak[2];
#pragma unroll
        for (int mt = 0; mt < 2; ++mt)
          ak[mt] = asbf(*(const u16x8*)&Ks[(mt * 16 + lc) * LSK + ks * 32 + quad * 8]);
#pragma unroll
        for (int mt = 0; mt < 2; ++mt)
#pragma unroll
          for (int nt = 0; nt < 2; ++nt)
            s[mt][nt] = __builtin_amdgcn_mfma_f32_16x16x32_bf16(ak[mt], bq[nt][ks],
                                                                s[mt][nt], 0, 0, 0);
      }

      // exp2 (scale pre-folded), mask only diagonal tile, truncating pack P^T
      const bool needmask = (t0 == qw);
#pragma unroll
      for (int mt = 0; mt < 2; ++mt)
#pragma unroll
        for (int nt = 0; nt < 2; ++nt) {
          float e[4];
#pragma unroll
          for (int r = 0; r < 4; ++r) {
            float v = s[mt][nt][r];
            if (needmask) {
              int tg = t0 + mt * 16 + quad * 4 + r;
              int qg = qw + nt * 16 + lc;
              v = (tg > qg) ? -1e30f : v;
            }
            e[r] = exp2f(v);
          }
          uint2 w;
          w.x = pktr(e[0], e[1]);
          w.y = pktr(e[2], e[3]);
          *(uint2*)&Ps[wave][(nt * 16 + lc) * LSV + mt * 16 + quad * 4] = w;
        }

      // O^T += V^T P^T  (m=d 80, n=q 32, k=t 32; dt=4 = ones-row -> l)
      bf16x8 av[5], bp[2];
#pragma unroll
      for (int dt = 0; dt < 5; ++dt)
        av[dt] = asbf(*(const u16x8*)&Vs[(dt * 16 + lc) * LSV + quad * 8]);
#pragma unroll
      for (int nt = 0; nt < 2; ++nt)
        bp[nt] = asbf(*(const u16x8*)&Ps[wave][(nt * 16 + lc) * LSV + quad * 8]);
#pragma unroll
      for (int dt = 0; dt < 5; ++dt)
#pragma unroll
        for (int nt = 0; nt < 2; ++nt)
          oacc[dt][nt] = __builtin_amdgcn_mfma_f32_16x16x32_bf16(av[dt], bp[nt],
                                                                 oacc[dt][nt], 0, 0, 0);
    }

    // epilogue: partial O^T (bf16) + partial l (fp32) for this chunk
#pragma unroll
    for (int nt = 0; nt < 2; ++nt) {
      const int qg = qw + nt * 16 + lc;
      u16* orow = Og + (size_t)qg * ND;
#pragma unroll
      for (int dt = 0; dt < 4; ++dt) {
        uint2 w;
        w.x = pkbf(oacc[dt][nt][0], oacc[dt][nt][1]);
        w.y = pkbf(oacc[dt][nt][2], oacc[dt][nt][3]);
        *(uint2*)&orow[dt * 16 + quad * 4] = w;
      }
      if (quad == 0) Lbase[qg] = oacc[4][nt][0];
    }
  }
}

// -------- combine 4 partials + normalize -> Y bf16 --------
__global__ void k_norm(const u16* __restrict__ O0, const u16* __restrict__ O1,
                       const u16* __restrict__ O2, const u16* __restrict__ O3,
                       const float* __restrict__ Lp, u16* __restrict__ Y) {
  const int S = NB * NH * NT;
  int idx = blockIdx.x * 256 + threadIdx.x;
  int row = idx >> 4, dg = idx & 15;
  int bh = row >> 12, q = row & (NT - 1);
  int b = bh / NH, h = bh - b * NH;
  const u16x4 a0 = *(const u16x4*)(O0 + (size_t)row * ND + dg * 4);
  const u16x4 a1 = *(const u16x4*)(O1 + (size_t)row * ND + dg * 4);
  const u16x4 a2 = *(const u16x4*)(O2 + (size_t)row * ND + dg * 4);
  const u16x4 a3 = *(const u16x4*)(O3 + (size_t)row * ND + dg * 4);
  float l = Lp[row] + Lp[row + S] + Lp[row + 2 * S] + Lp[row + 3 * S];
  float inv = 1.f / l;
  u16x4 y;
#pragma unroll
  for (int j = 0; j < 4; ++j)
    y[j] = f2bf((bf2f(a0[j]) + bf2f(a1[j]) + bf2f(a2[j]) + bf2f(a3[j])) * inv);
  *(u16x4*)&Y[((size_t)(b * NT + q)) * NC + h * 64 + dg * 4] = y;
}

extern "C" void kernel_launch(void* const* d_in, const int* in_sizes, int n_in,
                              void* d_out, int out_size, void* d_ws, size_t ws_size,
                              hipStream_t stream) {
  (void)in_sizes; (void)n_in; (void)out_size; (void)ws_size;
  const float* x = (const float*)d_in[0];
  const float* w_qkv = (const float*)d_in[1];
  const float* w_out = (const float*)d_in[2];
  float* out = (float*)d_out;

  u16* ws = (u16*)d_ws;
  const size_t XE = (size_t)NB * NT * NC;       // 6291456 elements
  u16* xb  = ws;                                // dead after QKV -> O0 overlay
  u16* wqT = xb + XE;
  u16* woT = wqT + (size_t)3 * NC * NC;
  u16* Qb  = woT + (size_t)NC * NC;
  u16* Kb  = Qb + XE;
  u16* Vtb = Kb + XE;
  u16* yb  = Vtb + XE;
  u16* O0  = xb;                                // overlay (x consumed by then)
  u16* O1  = (u16*)d_out;                       // d_out = 25 MB, holds 2 partials;
  u16* O2  = O1 + XE;                           // consumed by k_norm before final GEMM
  u16* O3  = yb + XE;
  float* Lp = (float*)(O3 + XE);                // 4 * NB*NH*NT floats

  k_cast<<<(int)(XE / 4 / 256), 256, 0, stream>>>(x, xb, (int)(XE / 4));
  k_transpose<<<dim3(3 * NC / 32, NC / 32), 256, 0, stream>>>(w_qkv, wqT, NC, 3 * NC);
  k_transpose<<<dim3(NC / 32, NC / 32), 256, 0, stream>>>(w_out, woT, NC, NC);
  k_gemm_bt<1><<<dim3(3 * NC / 128, NB * NT / 128), 256, 0, stream>>>(
      xb, wqT, NB * NT, 3 * NC, NC, Qb, Kb, Vtb, nullptr);
  k_attn<<<dim3(1536), 256, 0, stream>>>(Qb, Kb, Vtb, O0, O1, O2, O3, Lp);
  k_norm<<<(NB * NH * NT * 16) / 256, 256, 0, stream>>>(O0, O1, O2, O3, Lp, yb);
  k_gemm_bt<0><<<dim3(NC / 128, NB * NT / 128), 256, 0, stream>>>(
      yb, woT, NB * NT, NC, NC, nullptr, nullptr, nullptr, out);
}

// Round 6
// 274.551 us; speedup vs baseline: 5.0491x; 2.2165x over previous
//
#include <hip/hip_runtime.h>
#include <stdint.h>
#include <stddef.h>

#define NB 2
#define NT 4096
#define NC 768
#define NH 12
#define ND 64

typedef unsigned short u16;
typedef __attribute__((ext_vector_type(4))) float f32x4;
typedef __attribute__((ext_vector_type(8))) unsigned short u16x8;
typedef __attribute__((ext_vector_type(4))) unsigned short u16x4;
typedef __attribute__((ext_vector_type(8))) __bf16 bf16x8;

__device__ __forceinline__ u16 f2bf(float f) {
  uint32_t u = __builtin_bit_cast(uint32_t, f);
  u += 0x7FFFu + ((u >> 16) & 1u);   // RTNE
  return (u16)(u >> 16);
}
__device__ __forceinline__ bf16x8 asbf(u16x8 v) { return __builtin_bit_cast(bf16x8, v); }

// pack two f32 -> two bf16, round-half-up: 3 VALU
__device__ __forceinline__ uint32_t pkbf(float a, float b) {
  uint32_t ua = __builtin_bit_cast(uint32_t, a) + 0x8000u;
  uint32_t ub = __builtin_bit_cast(uint32_t, b) + 0x8000u;
  return __builtin_amdgcn_perm(ub, ua, 0x07060302u);
}
// truncating pack (P only; numerator/denominator stay consistent): 1 VALU
__device__ __forceinline__ uint32_t pktr(float a, float b) {
  return __builtin_amdgcn_perm(__builtin_bit_cast(uint32_t, b),
                               __builtin_bit_cast(uint32_t, a), 0x07060302u);
}

// ---------------- cast fp32 -> bf16 ----------------
__global__ void k_cast(const float* __restrict__ in, u16* __restrict__ out, int n4) {
  int i = blockIdx.x * blockDim.x + threadIdx.x;
  if (i < n4) {
    f32x4 v = ((const f32x4*)in)[i];
    u16x4 o;
    o[0] = f2bf(v[0]); o[1] = f2bf(v[1]); o[2] = f2bf(v[2]); o[3] = f2bf(v[3]);
    ((u16x4*)out)[i] = o;
  }
}

// -------- transpose + cast --------
__global__ void k_transpose(const float* __restrict__ in, u16* __restrict__ out,
                            int R, int Cn) {
  __shared__ float tile[32][33];
  int c0 = blockIdx.x * 32, r0 = blockIdx.y * 32;
  int tx = threadIdx.x & 31, ty = threadIdx.x >> 5;
  for (int i = ty; i < 32; i += 8)
    tile[i][tx] = in[(size_t)(r0 + i) * Cn + c0 + tx];
  __syncthreads();
  for (int i = ty; i < 32; i += 8)
    out[(size_t)(c0 + i) * R + r0 + tx] = f2bf(tile[tx][i]);
}

// -------- GEMM: C[M,N] = A[M,K] * Bt[N,K]^T --------
template <int EPI>
__global__ __launch_bounds__(256, 2)
void k_gemm_bt(const u16* __restrict__ A, const u16* __restrict__ Bt,
               int M, int N, int K,
               u16* __restrict__ o0, u16* __restrict__ o1, u16* __restrict__ o2,
               float* __restrict__ of) {
  __shared__ u16 As[128 * 40];
  __shared__ u16 Bs[128 * 40];
  const int tid = threadIdx.x;
  const int wave = tid >> 6, lane = tid & 63, quad = lane >> 4, lc = lane & 15;
  const int wm = (wave & 1) * 64, wn = (wave >> 1) * 64;
  const int bm = blockIdx.y * 128, bn = blockIdx.x * 128;

  const int sr = tid >> 2;
  const int sc8 = (tid & 3) * 8;
  const u16* ap0 = A + (size_t)(bm + sr) * K + sc8;
  const u16* ap1 = A + (size_t)(bm + 64 + sr) * K + sc8;
  const u16* bp0 = Bt + (size_t)(bn + sr) * K + sc8;
  const u16* bp1 = Bt + (size_t)(bn + 64 + sr) * K + sc8;
  u16* asl0 = &As[sr * 40 + sc8];
  u16* asl1 = &As[(64 + sr) * 40 + sc8];
  u16* bsl0 = &Bs[sr * 40 + sc8];
  u16* bsl1 = &Bs[(64 + sr) * 40 + sc8];

  f32x4 zv = {0.f, 0.f, 0.f, 0.f};
  f32x4 acc[4][4];
#pragma unroll
  for (int i = 0; i < 4; ++i)
#pragma unroll
    for (int j = 0; j < 4; ++j) acc[i][j] = zv;

  for (int k0 = 0; k0 < K; k0 += 32) {
    u16x8 a0 = *(const u16x8*)(ap0 + k0);
    u16x8 a1 = *(const u16x8*)(ap1 + k0);
    u16x8 b0 = *(const u16x8*)(bp0 + k0);
    u16x8 b1 = *(const u16x8*)(bp1 + k0);
    __syncthreads();
    *(u16x8*)asl0 = a0;
    *(u16x8*)asl1 = a1;
    *(u16x8*)bsl0 = b0;
    *(u16x8*)bsl1 = b1;
    __syncthreads();

    bf16x8 af[4], bfv[4];
#pragma unroll
    for (int mi = 0; mi < 4; ++mi)
      af[mi] = asbf(*(const u16x8*)&As[(wm + mi * 16 + lc) * 40 + quad * 8]);
#pragma unroll
    for (int ni = 0; ni < 4; ++ni)
      bfv[ni] = asbf(*(const u16x8*)&Bs[(wn + ni * 16 + lc) * 40 + quad * 8]);
#pragma unroll
    for (int mi = 0; mi < 4; ++mi)
#pragma unroll
      for (int ni = 0; ni < 4; ++ni)
        acc[mi][ni] = __builtin_amdgcn_mfma_f32_16x16x32_bf16(af[mi], bfv[ni],
                                                              acc[mi][ni], 0, 0, 0);
  }

  const int mrow0 = bm + wm + quad * 4;
#pragma unroll
  for (int mi = 0; mi < 4; ++mi) {
    const int mbase = mrow0 + mi * 16;
#pragma unroll
    for (int ni = 0; ni < 4; ++ni) {
      const int n = bn + wn + ni * 16 + lc;
      if (EPI == 0) {
#pragma unroll
        for (int r = 0; r < 4; ++r)
          of[(size_t)(mbase + r) * N + n] = acc[mi][ni][r];
      } else {
        const int sect = n / NC;          // 0=q 1=k 2=v
        const int wn2 = n - sect * NC;
        const int h = wn2 >> 6, d = wn2 & 63;
        const int b = mbase >> 12;
        const int t = mbase & (NT - 1);
        const float sc = (sect == 0) ? 0.18033688011112042f : 1.0f;  // log2e/8
        if (sect == 2) {
          u16x4 pk;
#pragma unroll
          for (int r = 0; r < 4; ++r) pk[r] = f2bf(acc[mi][ni][r]);
          *(u16x4*)&o2[((size_t)(b * NH + h) * ND + d) * NT + t] = pk;
        } else {
          u16* dst = (sect == 0) ? o0 : o1;
#pragma unroll
          for (int r = 0; r < 4; ++r)
            dst[((size_t)(b * NH + h) * NT + (t + r)) * ND + d] =
                f2bf(acc[mi][ni][r] * sc);
        }
      }
    }
  }
}

// -------- flash attention, causal, transposed, MERGED dual Q-tiles --------
// Block (bh, pair) owns Q-tiles qiA=pair, qiB=63-pair (64 rows each, 16/wave).
// KV tiles staged ONCE and used by both phases; all blocks walk t=0,1,2,...
// in lockstep -> device-wide hot window ~= #heads x 1 tile -> L2 hits without
// any XCD-placement assumption. No partials: full row-sum in-lane (ones-row
// appended to V^T computes l via MFMA), normalize inline, write Y once.
#define LSK 72   // Ks/Vs stride (64 + pad 8)
__global__ __launch_bounds__(256, 3)
void k_attn(const u16* __restrict__ Q, const u16* __restrict__ K,
            const u16* __restrict__ Vt, u16* __restrict__ Y) {
  __shared__ u16 Ks[64 * LSK];        // [t][d]
  __shared__ u16 Vs[80 * LSK];        // [d][t]; rows 64..79 static ones/zeros
  __shared__ u16 Ps[4 * 2 * 16 * LSK];// per-wave, per-phase P^T as [q][t]

  const int tid = threadIdx.x;
  const int wave = tid >> 6, lane = tid & 63, quad = lane >> 4, lc = lane & 15;
  const int bh = blockIdx.x >> 5, pair = blockIdx.x & 31;
  const int b = bh / NH, h = bh - b * NH;
  const u16* Qb = Q + (size_t)bh * NT * ND;
  const u16* Kb = K + (size_t)bh * NT * ND;
  const u16* Vb = Vt + (size_t)bh * ND * NT;

  // static Vs rows: row 64 = 1.0 (bf16), rows 65..79 = 0
  for (int idx = tid; idx < 16 * 64; idx += 256) {
    int r = idx >> 6, c = idx & 63;
    Vs[(64 + r) * LSK + c] = (r == 0) ? (u16)0x3F80 : (u16)0;
  }

  const int qwA = pair * 64 + wave * 16;
  const int qwB = (63 - pair) * 64 + wave * 16;
  u16* PsA = &Ps[(wave * 2 + 0) * 16 * LSK];
  u16* PsB = &Ps[(wave * 2 + 1) * 16 * LSK];

  // Q as B-operand fragments (scale log2(e)/8 pre-folded into Q)
  bf16x8 bqA[2], bqB[2];
#pragma unroll
  for (int ks = 0; ks < 2; ++ks) {
    bqA[ks] = asbf(*(const u16x8*)(Qb + (size_t)(qwA + lc) * ND + ks * 32 + quad * 8));
    bqB[ks] = asbf(*(const u16x8*)(Qb + (size_t)(qwB + lc) * ND + ks * 32 + quad * 8));
  }

  f32x4 zv = {0.f, 0.f, 0.f, 0.f};
  f32x4 oA[5], oB[5];                 // O^T [dtile 0..3], [4] = l row
#pragma unroll
  for (int dt = 0; dt < 5; ++dt) { oA[dt] = zv; oB[dt] = zv; }

  const int kr = tid >> 3, kc = (tid & 7) * 8;   // staging: 32 rows x 64 cols
  const int ntiles = 64 - pair;

  // prefetch tile 0
  u16x8 kv0 = *(const u16x8*)(Kb + (size_t)kr * ND + kc);
  u16x8 kv1 = *(const u16x8*)(Kb + (size_t)(32 + kr) * ND + kc);
  u16x8 vv0 = *(const u16x8*)(Vb + (size_t)kr * NT + kc);
  u16x8 vv1 = *(const u16x8*)(Vb + (size_t)(32 + kr) * NT + kc);

#pragma unroll 1
  for (int tau = 0; tau < ntiles; ++tau) {
    const int t0 = tau * 64;
    __syncthreads();
    *(u16x8*)&Ks[kr * LSK + kc] = kv0;
    *(u16x8*)&Ks[(32 + kr) * LSK + kc] = kv1;
    *(u16x8*)&Vs[kr * LSK + kc] = vv0;
    *(u16x8*)&Vs[(32 + kr) * LSK + kc] = vv1;
    __syncthreads();
    if (tau + 1 < ntiles) {
      const int tn = t0 + 64;
      kv0 = *(const u16x8*)(Kb + (size_t)(tn + kr) * ND + kc);
      kv1 = *(const u16x8*)(Kb + (size_t)(tn + 32 + kr) * ND + kc);
      vv0 = *(const u16x8*)(Vb + (size_t)kr * NT + tn + kc);
      vv1 = *(const u16x8*)(Vb + (size_t)(32 + kr) * NT + tn + kc);
    }

    const bool actA = (tau <= pair);   // block-uniform

    // S^T = K Q^T for both phases, sharing K fragments
    f32x4 sA[4], sB[4];
#pragma unroll
    for (int mt = 0; mt < 4; ++mt) { sA[mt] = zv; sB[mt] = zv; }
#pragma unroll
    for (int ks = 0; ks < 2; ++ks) {
      bf16x8 ak[4];
#pragma unroll
      for (int mt = 0; mt < 4; ++mt)
        ak[mt] = asbf(*(const u16x8*)&Ks[(mt * 16 + lc) * LSK + ks * 32 + quad * 8]);
      if (actA) {
#pragma unroll
        for (int mt = 0; mt < 4; ++mt)
          sA[mt] = __builtin_amdgcn_mfma_f32_16x16x32_bf16(ak[mt], bqA[ks], sA[mt], 0, 0, 0);
      }
#pragma unroll
      for (int mt = 0; mt < 4; ++mt)
        sB[mt] = __builtin_amdgcn_mfma_f32_16x16x32_bf16(ak[mt], bqB[ks], sB[mt], 0, 0, 0);
    }

    // exp2 + truncating pack -> Ps (P^T rows = q = lc)
    if (actA) {
      const bool mskA = (tau == pair);
#pragma unroll
      for (int mt = 0; mt < 4; ++mt) {
        float e[4];
#pragma unroll
        for (int r = 0; r < 4; ++r) {
          float v = sA[mt][r];
          if (mskA) {
            int tg = t0 + mt * 16 + quad * 4 + r;
            v = (tg > qwA + lc) ? -1e30f : v;
          }
          e[r] = exp2f(v);
        }
        uint2 w;
        w.x = pktr(e[0], e[1]);
        w.y = pktr(e[2], e[3]);
        *(uint2*)&PsA[lc * LSK + mt * 16 + quad * 4] = w;
      }
    }
    {
      const bool mskB = (tau == ntiles - 1);
#pragma unroll
      for (int mt = 0; mt < 4; ++mt) {
        float e[4];
#pragma unroll
        for (int r = 0; r < 4; ++r) {
          float v = sB[mt][r];
          if (mskB) {
            int tg = t0 + mt * 16 + quad * 4 + r;
            v = (tg > qwB + lc) ? -1e30f : v;
          }
          e[r] = exp2f(v);
        }
        uint2 w;
        w.x = pktr(e[0], e[1]);
        w.y = pktr(e[2], e[3]);
        *(uint2*)&PsB[lc * LSK + mt * 16 + quad * 4] = w;
      }
    }

    // O^T += V^T P^T for both phases, sharing V fragments
#pragma unroll
    for (int ks = 0; ks < 2; ++ks) {
      bf16x8 av[5];
#pragma unroll
      for (int dt = 0; dt < 5; ++dt)
        av[dt] = asbf(*(const u16x8*)&Vs[(dt * 16 + lc) * LSK + ks * 32 + quad * 8]);
      if (actA) {
        bf16x8 bp = asbf(*(const u16x8*)&PsA[lc * LSK + ks * 32 + quad * 8]);
#pragma unroll
        for (int dt = 0; dt < 5; ++dt)
          oA[dt] = __builtin_amdgcn_mfma_f32_16x16x32_bf16(av[dt], bp, oA[dt], 0, 0, 0);
      }
      {
        bf16x8 bp = asbf(*(const u16x8*)&PsB[lc * LSK + ks * 32 + quad * 8]);
#pragma unroll
        for (int dt = 0; dt < 5; ++dt)
          oB[dt] = __builtin_amdgcn_mfma_f32_16x16x32_bf16(av[dt], bp, oB[dt], 0, 0, 0);
      }
    }
  }

  // epilogue: l = row 64 of O^T (lane lc, quad 0, reg 0); normalize, write Y
#pragma unroll
  for (int phx = 0; phx < 2; ++phx) {
    const f32x4* o = phx ? oB : oA;
    const int qg = (phx ? qwB : qwA) + lc;
    float l = __shfl(o[4][0], lc);
    float inv = 1.f / l;
    u16* yrow = Y + (size_t)(b * NT + qg) * NC + h * 64;
#pragma unroll
    for (int dt = 0; dt < 4; ++dt) {
      uint2 w;
      w.x = pkbf(o[dt][0] * inv, o[dt][1] * inv);
      w.y = pkbf(o[dt][2] * inv, o[dt][3] * inv);
      *(uint2*)&yrow[dt * 16 + quad * 4] = w;
    }
  }
}

extern "C" void kernel_launch(void* const* d_in, const int* in_sizes, int n_in,
                              void* d_out, int out_size, void* d_ws, size_t ws_size,
                              hipStream_t stream) {
  (void)in_sizes; (void)n_in; (void)out_size; (void)ws_size;
  const float* x = (const float*)d_in[0];
  const float* w_qkv = (const float*)d_in[1];
  const float* w_out = (const float*)d_in[2];
  float* out = (float*)d_out;

  u16* ws = (u16*)d_ws;
  const size_t XE = (size_t)NB * NT * NC;       // 6291456 elements
  u16* xb  = ws;
  u16* wqT = xb + XE;
  u16* woT = wqT + (size_t)3 * NC * NC;
  u16* Qb  = woT + (size_t)NC * NC;
  u16* Kb  = Qb + XE;
  u16* Vtb = Kb + XE;
  u16* yb  = Vtb + XE;

  k_cast<<<(int)(XE / 4 / 256), 256, 0, stream>>>(x, xb, (int)(XE / 4));
  k_transpose<<<dim3(3 * NC / 32, NC / 32), 256, 0, stream>>>(w_qkv, wqT, NC, 3 * NC);
  k_transpose<<<dim3(NC / 32, NC / 32), 256, 0, stream>>>(w_out, woT, NC, NC);
  k_gemm_bt<1><<<dim3(3 * NC / 128, NB * NT / 128), 256, 0, stream>>>(
      xb, wqT, NB * NT, 3 * NC, NC, Qb, Kb, Vtb, nullptr);
  k_attn<<<dim3(32 * NB * NH), 256, 0, stream>>>(Qb, Kb, Vtb, yb);
  k_gemm_bt<0><<<dim3(NC / 128, NB * NT / 128), 256, 0, stream>>>(
      yb, woT, NB * NT, NC, NC, nullptr, nullptr, nullptr, out);
}